// Round 3
// baseline (419.714 us; speedup 1.0000x reference)
//
#include <hip/hip_runtime.h>
#include <cstdint>
#include <cstddef>

#define EPS 1e-6f

typedef short bf16x8 __attribute__((ext_vector_type(8)));
typedef float f32x4  __attribute__((ext_vector_type(4)));

__device__ __forceinline__ short f2bf(float x) {
    uint32_t u = __builtin_bit_cast(uint32_t, x);
    return (short)((u + 0x7FFFu + ((u >> 16) & 1u)) >> 16);
}

// ---------------------------------------------------------------------------
// Kernel FRONT: three independent sections in one launch.
//   blocks [0,16):    per-batch mask scan -> v_list + counts
//   blocks [16,784):  fp32->bf16 convert of W_fusion and W_down
//   blocks [784,1808): token rmsnorm -> bf16 rows (1 wave per 1024-elem row)
// ---------------------------------------------------------------------------
__global__ __launch_bounds__(256) void k_front(
    const void* __restrict__ maskp, int* __restrict__ v_list, int* __restrict__ counts,
    const float* __restrict__ Wf, short* __restrict__ Wfbf,
    const float* __restrict__ Wd, short* __restrict__ Wdbf,
    const float* __restrict__ tokens, const float* __restrict__ w_pre,
    short* __restrict__ tokbf) {
    const int blk = blockIdx.x, tid = threadIdx.x;
    if (blk < 16) {
        // ---- scan: 256 threads, 16 mask elems each ----
        __shared__ int wtot[4], woff[4];
        __shared__ int mode_s;
        const int b = blk, lane = tid & 63, wave = tid >> 6;
        if (tid == 0) mode_s = 0;
        __syncthreads();
        {
            int bad = 0;
#pragma unroll
            for (int q = 0; q < 4; ++q)
                bad |= (((const uint32_t*)maskp)[q * 256 + tid] > 1u) ? 1 : 0;
            if (bad) mode_s = 1;  // benign race
        }
        __syncthreads();
        int f[16];
        if (mode_s) {
            // byte bools: 16 bytes per thread
            const uint4 v = ((const uint4*)maskp)[(b << 8) + tid];
            const uint32_t ws[4] = {v.x, v.y, v.z, v.w};
#pragma unroll
            for (int q = 0; q < 4; ++q) {
                f[q * 4 + 0] = (ws[q] & 0x000000ffu) != 0;
                f[q * 4 + 1] = (ws[q] & 0x0000ff00u) != 0;
                f[q * 4 + 2] = (ws[q] & 0x00ff0000u) != 0;
                f[q * 4 + 3] = (ws[q] & 0xff000000u) != 0;
            }
        } else {
            // 4-byte bools: 16 words per thread
            const uint4* mp = (const uint4*)maskp + ((size_t)b << 10) + tid * 4;
#pragma unroll
            for (int q = 0; q < 4; ++q) {
                const uint4 v = mp[q];
                f[q * 4 + 0] = v.x != 0; f[q * 4 + 1] = v.y != 0;
                f[q * 4 + 2] = v.z != 0; f[q * 4 + 3] = v.w != 0;
            }
        }
        int c = 0;
#pragma unroll
        for (int q = 0; q < 16; ++q) c += f[q];
        int incl = c;
#pragma unroll
        for (int off = 1; off < 64; off <<= 1) {
            const int n = __shfl_up(incl, off);
            if (lane >= off) incl += n;
        }
        if (lane == 63) wtot[wave] = incl;
        __syncthreads();
        if (tid == 0) {
            int run = 0;
#pragma unroll
            for (int wv = 0; wv < 4; ++wv) { woff[wv] = run; run += wtot[wv]; }
            counts[b] = run;
        }
        __syncthreads();
        int base = woff[wave] + incl - c;
        int* vl = v_list + (b << 12);
        const int i0 = tid * 16;
#pragma unroll
        for (int q = 0; q < 16; ++q)
            if (f[q]) vl[base++] = i0 + q;
    } else if (blk < 784) {
        // ---- weight convert ----
        const int gid = (blk - 16) * 256 + tid;
        const float* s; short* d; int i;
        if (gid < 65536) { s = Wf; d = Wfbf; i = gid; }
        else             { s = Wd; d = Wdbf; i = gid - 65536; }
        const float4 v = ((const float4*)s)[i];
        short4 o;
        o.x = f2bf(v.x); o.y = f2bf(v.y); o.z = f2bf(v.z); o.w = f2bf(v.w);
        ((short4*)d)[i] = o;
    } else {
        // ---- token rmsnorm -> bf16 ----
        const int lane = tid & 63, wave = tid >> 6;
        const int row = (blk - 784) * 4 + wave;
        const float* xp = tokens + (size_t)row * 1024 + lane * 16;
        float4 x[4];
#pragma unroll
        for (int q = 0; q < 4; ++q) x[q] = *(const float4*)&xp[q * 4];
        float ss = 0.f;
#pragma unroll
        for (int q = 0; q < 4; ++q)
            ss += x[q].x * x[q].x + x[q].y * x[q].y + x[q].z * x[q].z + x[q].w * x[q].w;
#pragma unroll
        for (int off = 32; off > 0; off >>= 1) ss += __shfl_down(ss, off);
        ss = __shfl(ss, 0);
        const float r = rsqrtf(ss * (1.0f / 1024.0f) + EPS);
        const float* wp = w_pre + lane * 16;
        short* op = tokbf + (size_t)row * 1024 + lane * 16;
#pragma unroll
        for (int h = 0; h < 2; ++h) {
            bf16x8 o;
#pragma unroll
            for (int q = 0; q < 2; ++q) {
                const float4 wv = *(const float4*)&wp[h * 8 + q * 4];
                const float4 xv = x[h * 2 + q];
                o[q * 4 + 0] = f2bf(xv.x * wv.x * r);
                o[q * 4 + 1] = f2bf(xv.y * wv.y * r);
                o[q * 4 + 2] = f2bf(xv.z * wv.z * r);
                o[q * 4 + 3] = f2bf(xv.w * wv.w * r);
            }
            *(bf16x8*)&op[h * 8] = o;
        }
    }
}

// ---------------------------------------------------------------------------
// Kernel GT: token GEMM, K-split x2: partial[kt] = tokn[:, kt*512:+512] @ W^T.
// ---------------------------------------------------------------------------
__global__ __launch_bounds__(256) void k_gemm_tok(const short* __restrict__ tokbf,
                                                  const short* __restrict__ Wdbf,
                                                  float* __restrict__ feats) {
    __shared__ short As[128 * 32];
    __shared__ short Bs[128 * 32];
    const int tid = threadIdx.x, lane = tid & 63, w = tid >> 6;
    const int kt = blockIdx.x >> 7;
    const int mt = (blockIdx.x >> 2) & 31, nt = blockIdx.x & 3;
    const int wm = w >> 1, wn = w & 1;
    const int kbase = kt * 512;
    const short* hA = tokbf + (size_t)mt * 128 * 1024;
    const short* wB = Wdbf + (size_t)nt * 128 * 1024;

    f32x4 acc[4][4];
#pragma unroll
    for (int mi = 0; mi < 4; ++mi)
#pragma unroll
        for (int ni = 0; ni < 4; ++ni) acc[mi][ni] = (f32x4)0.f;

    const int rA = lane & 15, q8 = (lane >> 4) * 8;
    for (int kk = 0; kk < 512; kk += 32) {
#pragma unroll
        for (int q = 0; q < 2; ++q) {
            const int cid = (w * 2 + q) * 64 + lane;
            const int r = cid >> 2, kc = cid & 3;
            const size_t go = (size_t)r * 1024 + kbase + kk + kc * 8;
            __builtin_amdgcn_global_load_lds(
                (const __attribute__((address_space(1))) uint32_t*)(hA + go),
                (__attribute__((address_space(3))) uint32_t*)&As[(w * 2 + q) * 512], 16, 0, 0);
            __builtin_amdgcn_global_load_lds(
                (const __attribute__((address_space(1))) uint32_t*)(wB + go),
                (__attribute__((address_space(3))) uint32_t*)&Bs[(w * 2 + q) * 512], 16, 0, 0);
        }
        __syncthreads();
        bf16x8 af[4], bfr[4];
#pragma unroll
        for (int mi = 0; mi < 4; ++mi)
            af[mi] = *(const bf16x8*)&As[(wm * 64 + mi * 16 + rA) * 32 + q8];
#pragma unroll
        for (int ni = 0; ni < 4; ++ni)
            bfr[ni] = *(const bf16x8*)&Bs[(wn * 64 + ni * 16 + rA) * 32 + q8];
#pragma unroll
        for (int mi = 0; mi < 4; ++mi)
#pragma unroll
            for (int ni = 0; ni < 4; ++ni)
                acc[mi][ni] = __builtin_amdgcn_mfma_f32_16x16x32_bf16(af[mi], bfr[ni], acc[mi][ni], 0, 0, 0);
        __syncthreads();
    }
    float* fo = feats + (size_t)kt * 4096 * 512;
    const int rowb = mt * 128 + wm * 64 + (lane >> 4) * 4;
    const int colb = nt * 128 + wn * 64 + (lane & 15);
#pragma unroll
    for (int mi = 0; mi < 4; ++mi)
#pragma unroll
        for (int ni = 0; ni < 4; ++ni)
#pragma unroll
            for (int rg = 0; rg < 4; ++rg)
                fo[(size_t)(rowb + mi * 16 + rg) * 512 + colb + ni * 16] = acc[mi][ni][rg];
}

// ---------------------------------------------------------------------------
// Kernel A3: one wave per token: sum K-partials -> rmsnorm -> silu -> W_proj.
// ---------------------------------------------------------------------------
__global__ __launch_bounds__(64) void k_params(
    const float* __restrict__ feats_pre, const float* __restrict__ w_tok,
    const float* __restrict__ W_proj, float* __restrict__ params) {
    const int tk = blockIdx.x;
    const int lane = threadIdx.x;
    const int d0 = lane * 8;
    const float* fp0 = feats_pre + (size_t)tk * 512 + d0;
    const float* fp1 = fp0 + (size_t)4096 * 512;
    const float4 a0 = *(const float4*)&fp0[0];
    const float4 a1 = *(const float4*)&fp0[4];
    const float4 b0 = *(const float4*)&fp1[0];
    const float4 b1 = *(const float4*)&fp1[4];
    const float4 f0 = make_float4(a0.x + b0.x, a0.y + b0.y, a0.z + b0.z, a0.w + b0.w);
    const float4 f1 = make_float4(a1.x + b1.x, a1.y + b1.y, a1.z + b1.z, a1.w + b1.w);
    float ss = f0.x * f0.x + f0.y * f0.y + f0.z * f0.z + f0.w * f0.w
             + f1.x * f1.x + f1.y * f1.y + f1.z * f1.z + f1.w * f1.w;
#pragma unroll
    for (int off = 32; off > 0; off >>= 1) ss += __shfl_down(ss, off);
    ss = __shfl(ss, 0);
    const float rms = rsqrtf(ss * (1.0f / 512.0f) + EPS);

    const float4 wt0 = *(const float4*)&w_tok[d0];
    const float4 wt1 = *(const float4*)&w_tok[d0 + 4];
    float fv[8] = {f0.x, f0.y, f0.z, f0.w, f1.x, f1.y, f1.z, f1.w};
    float wv[8] = {wt0.x, wt0.y, wt0.z, wt0.w, wt1.x, wt1.y, wt1.z, wt1.w};
    float s[8];
#pragma unroll
    for (int j = 0; j < 8; ++j) {
        const float v = fv[j] * wv[j] * rms;
        s[j] = v / (1.0f + expf(-v));
    }
    float p[3];
#pragma unroll
    for (int q = 0; q < 3; ++q) {
        const float* Wp = W_proj + (size_t)q * 512 + d0;
        const float4 a = *(const float4*)&Wp[0];
        const float4 c = *(const float4*)&Wp[4];
        p[q] = s[0] * a.x + s[1] * a.y + s[2] * a.z + s[3] * a.w
             + s[4] * c.x + s[5] * c.y + s[6] * c.z + s[7] * c.w;
#pragma unroll
        for (int off = 32; off > 0; off >>= 1) p[q] += __shfl_down(p[q], off);
    }
    if (lane == 0) {
        float* po = params + (size_t)tk * 4;
        po[0] = 1.0f + p[0];
        po[1] = p[1];
        po[2] = 1.0f / (1.0f + expf(-p[2]));
        po[3] = 0.f;
    }
}

// ---------------------------------------------------------------------------
// Kernel GF: fused char-path GEMM.
//   pre-pass: rms over the block's 128 gathered char rows (cold fetch, warms L2)
//   K-loop:   reg-stage chars (L2-hot) -> modulated silu -> bf16 -> swizzled LDS
//             + reg-stage Wfus bf16; MFMA 128x128 tile.
//   epilogue: out = g*acc + (1-g)*cn (chars L2-hot), nontemporal stores.
//   rows >= cnt: filler. XCD-chunk swizzle groups the 4 nt-siblings per XCD.
// ---------------------------------------------------------------------------
__global__ __launch_bounds__(256) void k_gemm_fus(
    const short* __restrict__ Wbf, const float* __restrict__ chars,
    const float* __restrict__ w_char, const float* __restrict__ params,
    const int* __restrict__ v_list, const int* __restrict__ counts,
    const float* __restrict__ filler, float* __restrict__ out) {
    // bijective XCD chunk swizzle (2048 % 8 == 0)
    const int wg = (blockIdx.x & 7) * 256 + (blockIdx.x >> 3);
    const int b = wg >> 7;
    const int mt = (wg >> 2) & 31;
    const int nt = wg & 3;
    const int tid = threadIdx.x, lane = tid & 63, w = tid >> 6;
    const int cnt = counts[b];
    const int row0 = mt * 128;
    if (row0 >= cnt) {
        // pure filler tile
        const int colb0 = nt * 128;
        const f32x4 f = *(const f32x4*)(filler + colb0 + (tid & 31) * 4);
        float* o0 = out + ((size_t)(b << 12) + row0) * 512 + colb0 + (tid & 31) * 4;
        for (int r = tid >> 5; r < 128; r += 8)
            __builtin_nontemporal_store(f, (f32x4*)&o0[(size_t)r * 512]);
        return;
    }

    __shared__ short As[128 * 32];
    __shared__ short Bs[128 * 32];
    __shared__ float wc_s[512];
    __shared__ float rmsv[128], s1v[128], shv[128], gv[128];
    __shared__ int idxv[128];

    // w_char into LDS
    wc_s[tid] = w_char[tid];
    wc_s[tid + 256] = w_char[tid + 256];

    // per-row metadata
    if (tid < 128) {
        const int j = row0 + tid;
        const bool valid = j < cnt;
        const int idx = valid ? v_list[(b << 12) + j] : -1;
        idxv[tid] = idx;
        if (valid) {
            const float* pp = params + (size_t)((b << 8) + (idx >> 4)) * 4;
            s1v[tid] = pp[0]; shv[tid] = pp[1]; gv[tid] = pp[2];
        } else {
            s1v[tid] = 0.f; shv[tid] = 0.f; gv[tid] = 0.f;
        }
    }
    __syncthreads();

    // pre-pass: rms per row; 16 lanes per row, coalesced 256B segments
    {
        const int g16 = tid >> 4, l16 = tid & 15;
#pragma unroll
        for (int rr = 0; rr < 8; ++rr) {
            const int r = g16 * 8 + rr;
            const int id = idxv[r];
            float ss = 0.f;
            if (id >= 0) {
                const float* rp = chars + (((size_t)(b << 12) + id) << 9) + l16 * 4;
#pragma unroll
                for (int s = 0; s < 8; ++s) {
                    const float4 v = *(const float4*)&rp[s * 64];
                    ss += v.x * v.x + v.y * v.y + v.z * v.z + v.w * v.w;
                }
            }
#pragma unroll
            for (int off = 8; off > 0; off >>= 1) ss += __shfl_down(ss, off);
            if (l16 == 0) rmsv[r] = rsqrtf(ss * (1.0f / 512.0f) + EPS);
        }
    }
    __syncthreads();

    const int wm = w >> 1, wn = w & 1;
    f32x4 acc[4][4];
#pragma unroll
    for (int mi = 0; mi < 4; ++mi)
#pragma unroll
        for (int ni = 0; ni < 4; ++ni) acc[mi][ni] = (f32x4)0.f;

    // staging assignment: row r2 = tid>>1, 16-col half hf = tid&1
    const int r2 = tid >> 1, hf = tid & 1;
    const int swzA = ((r2 >> 1) & 3) << 3;  // element-XOR for 8-elem chunks
    const float rmsr = rmsv[r2], s1r = s1v[r2], shr = shv[r2];
    const int idr = idxv[r2];
    const float* arow = (idr >= 0) ? (chars + (((size_t)(b << 12) + idr) << 9)) : nullptr;
    const short* brow = Wbf + ((size_t)(nt * 128 + r2) << 9) + hf * 16;

    const int rA = lane & 15;
    const int ch = lane >> 4;  // frag chunk 0..3

    for (int kk = 0; kk < 512; kk += 32) {
        // --- stage B (bf16, L2-resident weight) ---
        const bf16x8 b0 = *(const bf16x8*)&brow[kk];
        const bf16x8 b1 = *(const bf16x8*)&brow[kk + 8];
        // --- stage A: chars f32 -> modulated silu -> bf16 ---
        bf16x8 a0, a1;
        if (idr >= 0) {
            const float* ap = arow + kk + hf * 16;
            const float4 x0 = *(const float4*)&ap[0];
            const float4 x1 = *(const float4*)&ap[4];
            const float4 x2 = *(const float4*)&ap[8];
            const float4 x3 = *(const float4*)&ap[12];
            const float xv[16] = {x0.x, x0.y, x0.z, x0.w, x1.x, x1.y, x1.z, x1.w,
                                  x2.x, x2.y, x2.z, x2.w, x3.x, x3.y, x3.z, x3.w};
            const float* wcp = &wc_s[kk + hf * 16];
            short tmp[16];
#pragma unroll
            for (int q = 0; q < 16; ++q) {
                const float cn = wcp[q] * xv[q] * rmsr;
                const float a = cn * s1r + shr;
                tmp[q] = f2bf(a / (1.0f + expf(-a)));
            }
#pragma unroll
            for (int q = 0; q < 8; ++q) { a0[q] = tmp[q]; a1[q] = tmp[q + 8]; }
        } else {
            a0 = (bf16x8)0; a1 = (bf16x8)0;
        }
        const int base = r2 * 32;
        *(bf16x8*)&As[base + (((hf * 2 + 0) << 3) ^ swzA)] = a0;
        *(bf16x8*)&As[base + (((hf * 2 + 1) << 3) ^ swzA)] = a1;
        *(bf16x8*)&Bs[base + (((hf * 2 + 0) << 3) ^ swzA)] = b0;
        *(bf16x8*)&Bs[base + (((hf * 2 + 1) << 3) ^ swzA)] = b1;
        __syncthreads();

        bf16x8 af[4], bfr[4];
#pragma unroll
        for (int mi = 0; mi < 4; ++mi) {
            const int row = wm * 64 + mi * 16 + rA;
            af[mi] = *(const bf16x8*)&As[row * 32 + ((ch ^ ((row >> 1) & 3)) << 3)];
        }
#pragma unroll
        for (int ni = 0; ni < 4; ++ni) {
            const int row = wn * 64 + ni * 16 + rA;
            bfr[ni] = *(const bf16x8*)&Bs[row * 32 + ((ch ^ ((row >> 1) & 3)) << 3)];
        }
#pragma unroll
        for (int mi = 0; mi < 4; ++mi)
#pragma unroll
            for (int ni = 0; ni < 4; ++ni)
                acc[mi][ni] = __builtin_amdgcn_mfma_f32_16x16x32_bf16(af[mi], bfr[ni], acc[mi][ni], 0, 0, 0);
        __syncthreads();
    }

    // epilogue: blend with cn (chars rows are L2-hot from pre-pass/K-loop)
    const int colb = nt * 128 + wn * 64 + (lane & 15);
    float wcv[4];
#pragma unroll
    for (int ni = 0; ni < 4; ++ni) wcv[ni] = wc_s[colb + ni * 16];
#pragma unroll
    for (int mi = 0; mi < 4; ++mi) {
#pragma unroll
        for (int rg = 0; rg < 4; ++rg) {
            const int jl = wm * 64 + mi * 16 + (lane >> 4) * 4 + rg;
            const int j = row0 + jl;
            const size_t orow = ((size_t)(b << 12) + j) * 512;
            if (j < cnt) {
                const float g = gv[jl], rm = rmsv[jl];
                const size_t xrow = ((size_t)(b << 12) + idxv[jl]) * 512;
#pragma unroll
                for (int ni = 0; ni < 4; ++ni) {
                    const int col = colb + ni * 16;
                    const float x = chars[xrow + col];
                    const float cn = wcv[ni] * x * rm;
                    __builtin_nontemporal_store(g * acc[mi][ni][rg] + (1.0f - g) * cn,
                                                &out[orow + col]);
                }
            } else {
#pragma unroll
                for (int ni = 0; ni < 4; ++ni) {
                    const int col = colb + ni * 16;
                    __builtin_nontemporal_store(filler[col], &out[orow + col]);
                }
            }
        }
    }
}

// ---------------------------------------------------------------------------
extern "C" void kernel_launch(void* const* d_in, const int* in_sizes, int n_in,
                              void* d_out, int out_size, void* d_ws, size_t ws_size,
                              hipStream_t stream) {
    const float* tokens = (const float*)d_in[0];
    const float* chars  = (const float*)d_in[2];
    const void*  cmask  = d_in[3];
    const float* filler = (const float*)d_in[4];
    const float* w_pre  = (const float*)d_in[5];
    const float* w_tok  = (const float*)d_in[6];
    const float* w_char = (const float*)d_in[7];
    const float* W_down = (const float*)d_in[8];
    const float* W_proj = (const float*)d_in[9];
    const float* W_fus  = (const float*)d_in[10];
    float* out = (float*)d_out;

    // workspace layout (~26 MB)
    float* feats_pre = (float*)d_ws;                          // 2 * 4096*512 f32 (16 MB)
    float* params    = feats_pre + (size_t)2 * 4096 * 512;    // 4096*4 f32
    int*   counts    = (int*)(params + (size_t)4096 * 4);     // 16
    int*   v_list    = counts + 16;                           // 65536
    short* Wbf       = (short*)(v_list + 65536);              // 512*512 bf16
    short* tokbf     = Wbf + (size_t)512 * 512;               // 4096*1024 bf16 (8 MB)
    short* Wdbf      = tokbf + (size_t)4096 * 1024;           // 512*1024 bf16 (1 MB)

    k_front<<<1808, 256, 0, stream>>>(cmask, v_list, counts, W_fus, Wbf,
                                      W_down, Wdbf, tokens, w_pre, tokbf);
    k_gemm_tok<<<256, 256, 0, stream>>>(tokbf, Wdbf, feats_pre);
    k_params<<<4096, 64, 0, stream>>>(feats_pre, w_tok, W_proj, params);
    k_gemm_fus<<<2048, 256, 0, stream>>>(Wbf, chars, w_char, params,
                                         v_list, counts, filler, out);
}

// Round 4
// 326.314 us; speedup vs baseline: 1.2862x; 1.2862x over previous
//
#include <hip/hip_runtime.h>
#include <cstdint>
#include <cstddef>

#define EPS 1e-6f

typedef short bf16x8 __attribute__((ext_vector_type(8)));
typedef float f32x4  __attribute__((ext_vector_type(4)));

__device__ __forceinline__ short f2bf(float x) {
    uint32_t u = __builtin_bit_cast(uint32_t, x);
    return (short)((u + 0x7FFFu + ((u >> 16) & 1u)) >> 16);
}

// ---------------------------------------------------------------------------
// Kernel FRONT: three independent sections in one launch.
//   blocks [0,16):    per-batch mask scan -> v_list + counts
//   blocks [16,784):  fp32->bf16 convert of W_fusion and W_down
//   blocks [784,1808): token rmsnorm -> bf16 rows (1 wave per 1024-elem row)
// ---------------------------------------------------------------------------
__global__ __launch_bounds__(256) void k_front(
    const void* __restrict__ maskp, int* __restrict__ v_list, int* __restrict__ counts,
    const float* __restrict__ Wf, short* __restrict__ Wfbf,
    const float* __restrict__ Wd, short* __restrict__ Wdbf,
    const float* __restrict__ tokens, const float* __restrict__ w_pre,
    short* __restrict__ tokbf) {
    const int blk = blockIdx.x, tid = threadIdx.x;
    if (blk < 16) {
        // ---- scan: 256 threads, 16 mask elems each ----
        __shared__ int wtot[4], woff[4];
        __shared__ int mode_s;
        const int b = blk, lane = tid & 63, wave = tid >> 6;
        if (tid == 0) mode_s = 0;
        __syncthreads();
        {
            int bad = 0;
#pragma unroll
            for (int q = 0; q < 4; ++q)
                bad |= (((const uint32_t*)maskp)[q * 256 + tid] > 1u) ? 1 : 0;
            if (bad) mode_s = 1;  // benign race
        }
        __syncthreads();
        int f[16];
        if (mode_s) {
            // byte bools: 16 bytes per thread
            const uint4 v = ((const uint4*)maskp)[(b << 8) + tid];
            const uint32_t ws[4] = {v.x, v.y, v.z, v.w};
#pragma unroll
            for (int q = 0; q < 4; ++q) {
                f[q * 4 + 0] = (ws[q] & 0x000000ffu) != 0;
                f[q * 4 + 1] = (ws[q] & 0x0000ff00u) != 0;
                f[q * 4 + 2] = (ws[q] & 0x00ff0000u) != 0;
                f[q * 4 + 3] = (ws[q] & 0xff000000u) != 0;
            }
        } else {
            // 4-byte bools: 16 words per thread
            const uint4* mp = (const uint4*)maskp + ((size_t)b << 10) + tid * 4;
#pragma unroll
            for (int q = 0; q < 4; ++q) {
                const uint4 v = mp[q];
                f[q * 4 + 0] = v.x != 0; f[q * 4 + 1] = v.y != 0;
                f[q * 4 + 2] = v.z != 0; f[q * 4 + 3] = v.w != 0;
            }
        }
        int c = 0;
#pragma unroll
        for (int q = 0; q < 16; ++q) c += f[q];
        int incl = c;
#pragma unroll
        for (int off = 1; off < 64; off <<= 1) {
            const int n = __shfl_up(incl, off);
            if (lane >= off) incl += n;
        }
        if (lane == 63) wtot[wave] = incl;
        __syncthreads();
        if (tid == 0) {
            int run = 0;
#pragma unroll
            for (int wv = 0; wv < 4; ++wv) { woff[wv] = run; run += wtot[wv]; }
            counts[b] = run;
        }
        __syncthreads();
        int base = woff[wave] + incl - c;
        int* vl = v_list + (b << 12);
        const int i0 = tid * 16;
#pragma unroll
        for (int q = 0; q < 16; ++q)
            if (f[q]) vl[base++] = i0 + q;
    } else if (blk < 784) {
        // ---- weight convert ----
        const int gid = (blk - 16) * 256 + tid;
        const float* s; short* d; int i;
        if (gid < 65536) { s = Wf; d = Wfbf; i = gid; }
        else             { s = Wd; d = Wdbf; i = gid - 65536; }
        const float4 v = ((const float4*)s)[i];
        short4 o;
        o.x = f2bf(v.x); o.y = f2bf(v.y); o.z = f2bf(v.z); o.w = f2bf(v.w);
        ((short4*)d)[i] = o;
    } else {
        // ---- token rmsnorm -> bf16 ----
        const int lane = tid & 63, wave = tid >> 6;
        const int row = (blk - 784) * 4 + wave;
        const float* xp = tokens + (size_t)row * 1024 + lane * 16;
        float4 x[4];
#pragma unroll
        for (int q = 0; q < 4; ++q) x[q] = *(const float4*)&xp[q * 4];
        float ss = 0.f;
#pragma unroll
        for (int q = 0; q < 4; ++q)
            ss += x[q].x * x[q].x + x[q].y * x[q].y + x[q].z * x[q].z + x[q].w * x[q].w;
#pragma unroll
        for (int off = 32; off > 0; off >>= 1) ss += __shfl_down(ss, off);
        ss = __shfl(ss, 0);
        const float r = rsqrtf(ss * (1.0f / 1024.0f) + EPS);
        const float* wp = w_pre + lane * 16;
        short* op = tokbf + (size_t)row * 1024 + lane * 16;
#pragma unroll
        for (int h = 0; h < 2; ++h) {
            bf16x8 o;
#pragma unroll
            for (int q = 0; q < 2; ++q) {
                const float4 wv = *(const float4*)&wp[h * 8 + q * 4];
                const float4 xv = x[h * 2 + q];
                o[q * 4 + 0] = f2bf(xv.x * wv.x * r);
                o[q * 4 + 1] = f2bf(xv.y * wv.y * r);
                o[q * 4 + 2] = f2bf(xv.z * wv.z * r);
                o[q * 4 + 3] = f2bf(xv.w * wv.w * r);
            }
            *(bf16x8*)&op[h * 8] = o;
        }
    }
}

// ---------------------------------------------------------------------------
// Kernel GT: token GEMM, K-split x2: partial[kt] = tokn[:, kt*512:+512] @ W^T.
// LDS chunk-XOR swizzle applied via pre-swizzled global source (rule #21):
// global_load_lds writes linearly, so XOR the global k-chunk and apply the
// same XOR on the fragment ds_read (round-3 counters: conflicts -> 0).
// ---------------------------------------------------------------------------
__global__ __launch_bounds__(256) void k_gemm_tok(const short* __restrict__ tokbf,
                                                  const short* __restrict__ Wdbf,
                                                  float* __restrict__ feats) {
    __shared__ short As[128 * 32];
    __shared__ short Bs[128 * 32];
    const int tid = threadIdx.x, lane = tid & 63, w = tid >> 6;
    const int kt = blockIdx.x >> 7;
    const int mt = (blockIdx.x >> 2) & 31, nt = blockIdx.x & 3;
    const int wm = w >> 1, wn = w & 1;
    const int kbase = kt * 512;
    const short* hA = tokbf + (size_t)mt * 128 * 1024;
    const short* wB = Wdbf + (size_t)nt * 128 * 1024;

    f32x4 acc[4][4];
#pragma unroll
    for (int mi = 0; mi < 4; ++mi)
#pragma unroll
        for (int ni = 0; ni < 4; ++ni) acc[mi][ni] = (f32x4)0.f;

    const int rA = lane & 15, ch = lane >> 4;
    for (int kk = 0; kk < 512; kk += 32) {
#pragma unroll
        for (int q = 0; q < 2; ++q) {
            const int cid = (w * 2 + q) * 64 + lane;
            const int r = cid >> 2, kc = cid & 3;
            const int kcs = kc ^ ((r >> 1) & 3);  // pre-swizzled source chunk
            const size_t go = (size_t)r * 1024 + kbase + kk + kcs * 8;
            __builtin_amdgcn_global_load_lds(
                (const __attribute__((address_space(1))) uint32_t*)(hA + go),
                (__attribute__((address_space(3))) uint32_t*)&As[(w * 2 + q) * 512], 16, 0, 0);
            __builtin_amdgcn_global_load_lds(
                (const __attribute__((address_space(1))) uint32_t*)(wB + go),
                (__attribute__((address_space(3))) uint32_t*)&Bs[(w * 2 + q) * 512], 16, 0, 0);
        }
        __syncthreads();
        bf16x8 af[4], bfr[4];
#pragma unroll
        for (int mi = 0; mi < 4; ++mi) {
            const int row = wm * 64 + mi * 16 + rA;
            af[mi] = *(const bf16x8*)&As[row * 32 + ((ch ^ ((row >> 1) & 3)) << 3)];
        }
#pragma unroll
        for (int ni = 0; ni < 4; ++ni) {
            const int row = wn * 64 + ni * 16 + rA;
            bfr[ni] = *(const bf16x8*)&Bs[row * 32 + ((ch ^ ((row >> 1) & 3)) << 3)];
        }
#pragma unroll
        for (int mi = 0; mi < 4; ++mi)
#pragma unroll
            for (int ni = 0; ni < 4; ++ni)
                acc[mi][ni] = __builtin_amdgcn_mfma_f32_16x16x32_bf16(af[mi], bfr[ni], acc[mi][ni], 0, 0, 0);
        __syncthreads();
    }
    float* fo = feats + (size_t)kt * 4096 * 512;
    const int rowb = mt * 128 + wm * 64 + (lane >> 4) * 4;
    const int colb = nt * 128 + wn * 64 + (lane & 15);
#pragma unroll
    for (int mi = 0; mi < 4; ++mi)
#pragma unroll
        for (int ni = 0; ni < 4; ++ni)
#pragma unroll
            for (int rg = 0; rg < 4; ++rg)
                fo[(size_t)(rowb + mi * 16 + rg) * 512 + colb + ni * 16] = acc[mi][ni][rg];
}

// ---------------------------------------------------------------------------
// Kernel A3: one wave per token: sum K-partials -> rmsnorm -> silu -> W_proj.
// ---------------------------------------------------------------------------
__global__ __launch_bounds__(64) void k_params(
    const float* __restrict__ feats_pre, const float* __restrict__ w_tok,
    const float* __restrict__ W_proj, float* __restrict__ params) {
    const int tk = blockIdx.x;
    const int lane = threadIdx.x;
    const int d0 = lane * 8;
    const float* fp0 = feats_pre + (size_t)tk * 512 + d0;
    const float* fp1 = fp0 + (size_t)4096 * 512;
    const float4 a0 = *(const float4*)&fp0[0];
    const float4 a1 = *(const float4*)&fp0[4];
    const float4 b0 = *(const float4*)&fp1[0];
    const float4 b1 = *(const float4*)&fp1[4];
    const float4 f0 = make_float4(a0.x + b0.x, a0.y + b0.y, a0.z + b0.z, a0.w + b0.w);
    const float4 f1 = make_float4(a1.x + b1.x, a1.y + b1.y, a1.z + b1.z, a1.w + b1.w);
    float ss = f0.x * f0.x + f0.y * f0.y + f0.z * f0.z + f0.w * f0.w
             + f1.x * f1.x + f1.y * f1.y + f1.z * f1.z + f1.w * f1.w;
#pragma unroll
    for (int off = 32; off > 0; off >>= 1) ss += __shfl_down(ss, off);
    ss = __shfl(ss, 0);
    const float rms = rsqrtf(ss * (1.0f / 512.0f) + EPS);

    const float4 wt0 = *(const float4*)&w_tok[d0];
    const float4 wt1 = *(const float4*)&w_tok[d0 + 4];
    float fv[8] = {f0.x, f0.y, f0.z, f0.w, f1.x, f1.y, f1.z, f1.w};
    float wv[8] = {wt0.x, wt0.y, wt0.z, wt0.w, wt1.x, wt1.y, wt1.z, wt1.w};
    float s[8];
#pragma unroll
    for (int j = 0; j < 8; ++j) {
        const float v = fv[j] * wv[j] * rms;
        s[j] = v / (1.0f + expf(-v));
    }
    float p[3];
#pragma unroll
    for (int q = 0; q < 3; ++q) {
        const float* Wp = W_proj + (size_t)q * 512 + d0;
        const float4 a = *(const float4*)&Wp[0];
        const float4 c = *(const float4*)&Wp[4];
        p[q] = s[0] * a.x + s[1] * a.y + s[2] * a.z + s[3] * a.w
             + s[4] * c.x + s[5] * c.y + s[6] * c.z + s[7] * c.w;
#pragma unroll
        for (int off = 32; off > 0; off >>= 1) p[q] += __shfl_down(p[q], off);
    }
    if (lane == 0) {
        float* po = params + (size_t)tk * 4;
        po[0] = 1.0f + p[0];
        po[1] = p[1];
        po[2] = 1.0f / (1.0f + expf(-p[2]));
        po[3] = 0.f;
    }
}

// ---------------------------------------------------------------------------
// Kernel CP: char prep. One wave per compact slot j: rmsnorm -> modulated silu
// -> bf16 h row (computed ONCE per row; round-3 showed in-GEMM recompute is
// 4x redundant VALU and regresses). Zero-pads rows to 128-multiple.
// ---------------------------------------------------------------------------
__global__ __launch_bounds__(256) void k_prep(
    const float* __restrict__ chars, const float* __restrict__ w_char,
    const float* __restrict__ params, const int* __restrict__ v_list,
    const int* __restrict__ counts, short* __restrict__ hb,
    float* __restrict__ rms_l, float* __restrict__ g_l) {
    const int tid = threadIdx.x, lane = tid & 63, wave = tid >> 6;
    const int b = blockIdx.x >> 10;
    const int j = (blockIdx.x & 1023) * 4 + wave;
    const int cnt = counts[b];
    const int cpad = (cnt + 127) & ~127;
    if (j >= cpad) return;
    short* hrow = hb + ((size_t)(b << 12) + j) * 512 + lane * 8;
    if (j >= cnt) {
        *(bf16x8*)hrow = (bf16x8)0;
        return;
    }
    const int i = v_list[(b << 12) + j];
    const float* xp = chars + ((size_t)(b << 12) + i) * 512 + lane * 8;
    const float4 x0 = *(const float4*)&xp[0];
    const float4 x1 = *(const float4*)&xp[4];
    float ss = x0.x * x0.x + x0.y * x0.y + x0.z * x0.z + x0.w * x0.w
             + x1.x * x1.x + x1.y * x1.y + x1.z * x1.z + x1.w * x1.w;
#pragma unroll
    for (int off = 32; off > 0; off >>= 1) ss += __shfl_down(ss, off);
    ss = __shfl(ss, 0);
    const float rms = rsqrtf(ss * (1.0f / 512.0f) + EPS);
    const float* pp = params + (size_t)((b << 8) + (i >> 4)) * 4;
    const float s1 = pp[0], sh = pp[1], g = pp[2];
    const float4 w0 = *(const float4*)&w_char[lane * 8];
    const float4 w1 = *(const float4*)&w_char[lane * 8 + 4];
    float xv[8] = {x0.x, x0.y, x0.z, x0.w, x1.x, x1.y, x1.z, x1.w};
    float wv[8] = {w0.x, w0.y, w0.z, w0.w, w1.x, w1.y, w1.z, w1.w};
    bf16x8 o;
#pragma unroll
    for (int q = 0; q < 8; ++q) {
        const float cn = wv[q] * xv[q] * rms;
        const float a = cn * s1 + sh;
        o[q] = f2bf(a / (1.0f + expf(-a)));
    }
    *(bf16x8*)hrow = o;
    if (lane == 0) {
        rms_l[(b << 12) + j] = rms;
        g_l[(b << 12) + j] = g;
    }
}

// ---------------------------------------------------------------------------
// Kernel GF: fusion GEMM out[rows<cnt] = g*(h @ Wfus^T) + (1-g)*cn over
// compacted rows; rows >= cnt get filler_embed. global_load_lds staging with
// pre-swizzled source (conflict-free fragment reads), XCD chunk swizzle,
// nontemporal output stores.
// ---------------------------------------------------------------------------
__global__ __launch_bounds__(256) void k_gemm_fus(
    const short* __restrict__ hb, const short* __restrict__ Wbf,
    const float* __restrict__ chars, const float* __restrict__ w_char,
    const float* __restrict__ rms_l, const float* __restrict__ g_l,
    const int* __restrict__ v_list, const int* __restrict__ counts,
    const float* __restrict__ filler, float* __restrict__ out) {
    // bijective XCD chunk swizzle (2048 % 8 == 0): nt-siblings share one XCD L2
    const int wg = (blockIdx.x & 7) * 256 + (blockIdx.x >> 3);
    const int b = wg >> 7;
    const int mt = (wg >> 2) & 31;
    const int nt = wg & 3;
    const int tid = threadIdx.x, lane = tid & 63, w = tid >> 6;
    const int cnt = counts[b];
    const int row0 = mt * 128;
    if (row0 >= cnt) {
        // pure filler tile
        const int colb0 = nt * 128;
        const f32x4 f = *(const f32x4*)(filler + colb0 + (tid & 31) * 4);
        float* o0 = out + ((size_t)(b << 12) + row0) * 512 + colb0 + (tid & 31) * 4;
        for (int r = tid >> 5; r < 128; r += 8)
            __builtin_nontemporal_store(f, (f32x4*)&o0[(size_t)r * 512]);
        return;
    }

    __shared__ short As[128 * 32];
    __shared__ short Bs[128 * 32];
    __shared__ float g_s[128], rms_s[128];
    __shared__ int idx_s[128];
    const int wm = w >> 1, wn = w & 1;

    if (tid < 128) {
        const int j = row0 + tid;
        const bool valid = j < cnt;
        idx_s[tid] = valid ? v_list[(b << 12) + j] : 0;
        g_s[tid]   = valid ? g_l[(b << 12) + j] : 0.f;
        rms_s[tid] = valid ? rms_l[(b << 12) + j] : 0.f;
    }

    const short* hA = hb + ((size_t)(b << 12) + row0) * 512;
    const short* wB = Wbf + (size_t)nt * 128 * 512;

    f32x4 acc[4][4];
#pragma unroll
    for (int mi = 0; mi < 4; ++mi)
#pragma unroll
        for (int ni = 0; ni < 4; ++ni) acc[mi][ni] = (f32x4)0.f;

    const int rA = lane & 15, ch = lane >> 4;
    for (int kk = 0; kk < 512; kk += 32) {
#pragma unroll
        for (int q = 0; q < 2; ++q) {
            const int cid = (w * 2 + q) * 64 + lane;
            const int r = cid >> 2, kc = cid & 3;
            const int kcs = kc ^ ((r >> 1) & 3);  // pre-swizzled source chunk
            const size_t go = (size_t)r * 512 + kk + kcs * 8;
            __builtin_amdgcn_global_load_lds(
                (const __attribute__((address_space(1))) uint32_t*)(hA + go),
                (__attribute__((address_space(3))) uint32_t*)&As[(w * 2 + q) * 512], 16, 0, 0);
            __builtin_amdgcn_global_load_lds(
                (const __attribute__((address_space(1))) uint32_t*)(wB + go),
                (__attribute__((address_space(3))) uint32_t*)&Bs[(w * 2 + q) * 512], 16, 0, 0);
        }
        __syncthreads();
        bf16x8 af[4], bfr[4];
#pragma unroll
        for (int mi = 0; mi < 4; ++mi) {
            const int row = wm * 64 + mi * 16 + rA;
            af[mi] = *(const bf16x8*)&As[row * 32 + ((ch ^ ((row >> 1) & 3)) << 3)];
        }
#pragma unroll
        for (int ni = 0; ni < 4; ++ni) {
            const int row = wn * 64 + ni * 16 + rA;
            bfr[ni] = *(const bf16x8*)&Bs[row * 32 + ((ch ^ ((row >> 1) & 3)) << 3)];
        }
#pragma unroll
        for (int mi = 0; mi < 4; ++mi)
#pragma unroll
            for (int ni = 0; ni < 4; ++ni)
                acc[mi][ni] = __builtin_amdgcn_mfma_f32_16x16x32_bf16(af[mi], bfr[ni], acc[mi][ni], 0, 0, 0);
        __syncthreads();
    }

    // epilogue: blend with cn; nontemporal stores (out never re-read)
    const int colb = nt * 128 + wn * 64 + (lane & 15);
    float wcv[4];
#pragma unroll
    for (int ni = 0; ni < 4; ++ni) wcv[ni] = w_char[colb + ni * 16];
#pragma unroll
    for (int mi = 0; mi < 4; ++mi) {
#pragma unroll
        for (int rg = 0; rg < 4; ++rg) {
            const int jl = wm * 64 + mi * 16 + (lane >> 4) * 4 + rg;
            const int j = row0 + jl;
            const size_t orow = ((size_t)(b << 12) + j) * 512;
            if (j < cnt) {
                const float g = g_s[jl], rm = rms_s[jl];
                const size_t xrow = ((size_t)(b << 12) + idx_s[jl]) * 512;
#pragma unroll
                for (int ni = 0; ni < 4; ++ni) {
                    const int col = colb + ni * 16;
                    const float x = chars[xrow + col];
                    const float cn = wcv[ni] * x * rm;
                    __builtin_nontemporal_store(g * acc[mi][ni][rg] + (1.0f - g) * cn,
                                                &out[orow + col]);
                }
            } else {
#pragma unroll
                for (int ni = 0; ni < 4; ++ni) {
                    const int col = colb + ni * 16;
                    __builtin_nontemporal_store(filler[col], &out[orow + col]);
                }
            }
        }
    }
}

// ---------------------------------------------------------------------------
extern "C" void kernel_launch(void* const* d_in, const int* in_sizes, int n_in,
                              void* d_out, int out_size, void* d_ws, size_t ws_size,
                              hipStream_t stream) {
    const float* tokens = (const float*)d_in[0];
    const float* chars  = (const float*)d_in[2];
    const void*  cmask  = d_in[3];
    const float* filler = (const float*)d_in[4];
    const float* w_pre  = (const float*)d_in[5];
    const float* w_tok  = (const float*)d_in[6];
    const float* w_char = (const float*)d_in[7];
    const float* W_down = (const float*)d_in[8];
    const float* W_proj = (const float*)d_in[9];
    const float* W_fus  = (const float*)d_in[10];
    float* out = (float*)d_out;

    // workspace layout (~91 MB)
    float* feats_pre = (float*)d_ws;                          // 2 * 4096*512 f32 (16 MB)
    float* params    = feats_pre + (size_t)2 * 4096 * 512;    // 4096*4 f32
    int*   counts    = (int*)(params + (size_t)4096 * 4);     // 16
    int*   v_list    = counts + 16;                           // 65536
    float* rms_l     = (float*)(v_list + 65536);              // 65536
    float* g_l       = rms_l + 65536;                         // 65536
    short* Wbf       = (short*)(g_l + 65536);                 // 512*512 bf16
    short* hb        = Wbf + (size_t)512 * 512;               // 16*4096*512 bf16 (64 MB)
    short* tokbf     = hb + (size_t)16 * 4096 * 512;          // 4096*1024 bf16 (8 MB)
    short* Wdbf      = tokbf + (size_t)4096 * 1024;           // 512*1024 bf16 (1 MB)

    k_front<<<1808, 256, 0, stream>>>(cmask, v_list, counts, W_fus, Wbf,
                                      W_down, Wdbf, tokens, w_pre, tokbf);
    k_gemm_tok<<<256, 256, 0, stream>>>(tokbf, Wdbf, feats_pre);
    k_params<<<4096, 64, 0, stream>>>(feats_pre, w_tok, W_proj, params);
    k_prep<<<16384, 256, 0, stream>>>(chars, w_char, params, v_list, counts, hb, rms_l, g_l);
    k_gemm_fus<<<2048, 256, 0, stream>>>(hb, Wbf, chars, w_char, rms_l, g_l,
                                         v_list, counts, filler, out);
}